// Round 8
// baseline (2035.532 us; speedup 1.0000x reference)
//
#include <hip/hip_runtime.h>
#include <math.h>

#define NORB 256
#define NF 128

__device__ __forceinline__ float rdlane(float v, int sl) {
    return __uint_as_float((unsigned)__builtin_amdgcn_readlane((int)__float_as_uint(v), sl));
}

// ---- update + extract column J; broadcast row comes from LO / HI register half ----
#define UXL(J) case J: { const float u = rdlane(rlo[J], psl); \
    clo = rlo[J] = fmaf(nl, u, rlo[J]); \
    chi = rhi[J] = fmaf(nh, u, rhi[J]); } break;
#define UXH(J) case J: { const float u = rdlane(rhi[J], psl); \
    clo = rlo[J] = fmaf(nl, u, rlo[J]); \
    chi = rhi[J] = fmaf(nh, u, rhi[J]); } break;
#define UXL8(J) UXL(J) UXL(J+1) UXL(J+2) UXL(J+3) UXL(J+4) UXL(J+5) UXL(J+6) UXL(J+7)
#define UXH8(J) UXH(J) UXH(J+1) UXH(J+2) UXH(J+3) UXH(J+4) UXH(J+5) UXH(J+6) UXH(J+7)

// ---- plain unrolled quarter-update (32 columns), no switch ----
#define QL(Q0) { _Pragma("unroll") for (int j = Q0; j < Q0 + 32; ++j) { \
    const float u = rdlane(rlo[j], psl); \
    rlo[j] = fmaf(nl, u, rlo[j]); \
    rhi[j] = fmaf(nh, u, rhi[j]); } }
#define QH(Q0) { _Pragma("unroll") for (int j = Q0; j < Q0 + 32; ++j) { \
    const float u = rdlane(rhi[j], psl); \
    rlo[j] = fmaf(nl, u, rlo[j]); \
    rhi[j] = fmaf(nh, u, rhi[j]); } }

// masked wave max of |clo|,|chi| -> cmax (mlo/mhi are per-lane masked keys)
#define MAXCHAIN() do { \
    mlo = alive_lo ? fabsf(clo) : 0.f; \
    mhi = alive_hi ? fabsf(chi) : 0.f; \
    float cm = fmaxf(mlo, mhi); \
    _Pragma("unroll") \
    for (int mm = 32; mm; mm >>= 1) cm = fmaxf(cm, __shfl_xor(cm, mm)); \
    cmax = cm; \
} while (0)

__global__ __launch_bounds__(64, 1)
void slogdet_pp3_kernel(const int* __restrict__ n, const float* __restrict__ M,
                        float* __restrict__ out, int batch)
{
    __shared__ int R[NF];
    __shared__ int plist[NF];

    const int lane = threadIdx.x;
    const int b    = blockIdx.x;

    // ---------- occupied indices (ascending) ----------
    const unsigned long long lmask_lt = (1ULL << lane) - 1ULL;
    int prevtotal = 0;
    #pragma unroll
    for (int seg = 0; seg < 4; ++seg) {
        const int o = seg * 64 + lane;
        const int occ = (n[b * NORB + o] != 0);
        const unsigned long long m = __ballot(occ);
        const int pre = __popcll(m & lmask_lt);
        if (occ) R[prevtotal + pre] = o;
        prevtotal += __popcll(m);
    }
    __syncthreads();

    // ---------- gather 2 rows per lane into registers ----------
    float rlo[128], rhi[128];
    {
        const float4* m0 = (const float4*)(M + R[lane] * NF);
        const float4* m1 = (const float4*)(M + R[lane + 64] * NF);
        #pragma unroll
        for (int j4 = 0; j4 < 32; ++j4) {
            const float4 v0 = m0[j4];
            rlo[4*j4+0] = v0.x; rlo[4*j4+1] = v0.y; rlo[4*j4+2] = v0.z; rlo[4*j4+3] = v0.w;
            const float4 v1 = m1[j4];
            rhi[4*j4+0] = v1.x; rhi[4*j4+1] = v1.y; rhi[4*j4+2] = v1.z; rhi[4*j4+3] = v1.w;
        }
    }

    bool alive_lo = true, alive_hi = true;
    float acc = 0.f;
    int   neg = 0;

    float clo = rlo[0], chi = rhi[0];
    float mlo, mhi, cmax;
    MAXCHAIN();

    #pragma unroll 1
    for (int k = 0; k < 127; ++k) {
        // ---- pivot = first row whose masked |v| equals the wave max ----
        const unsigned long long blo = __ballot(mlo == cmax);
        const unsigned long long bhi = __ballot(mhi == cmax);
        int p;
        if (blo)      p = __ffsll(blo) - 1;
        else if (bhi) p = 64 + __ffsll(bhi) - 1;
        else          p = 0;   // defensive (NaN column) — keeps behavior defined
        const int ps  = __builtin_amdgcn_readfirstlane(p);
        const int psl = ps & 63;
        const float pv = rdlane(ps >= 64 ? chi : clo, psl);
        if (lane == 0) plist[k] = ps;
        acc += __log2f(fabsf(pv));
        neg += (pv < 0.f) ? 1 : 0;

        const float rp = 1.0f / pv;
        const float nl = alive_lo ? -(clo * rp) : 0.f;   // pivot lane gets ~-1 -> row annihilated
        const float nh = alive_hi ? -(chi * rp) : 0.f;
        alive_lo = alive_lo && (ps != lane);
        alive_hi = alive_hi && (ps != 64 + lane);

        // ---- update + extract column k+1 FIRST (feeds next argmax) ----
        if (ps < 64) {
            switch (k + 1) {
                UXL8(1)  UXL8(9)  UXL8(17) UXL8(25) UXL8(33) UXL8(41) UXL8(49) UXL8(57)
                UXL8(65) UXL8(73) UXL8(81) UXL8(89) UXL8(97) UXL8(105) UXL8(113)
                UXL(121) UXL(122) UXL(123) UXL(124) UXL(125) UXL(126) UXL(127)
                default: break;
            }
        } else {
            switch (k + 1) {
                UXH8(1)  UXH8(9)  UXH8(17) UXH8(25) UXH8(33) UXH8(41) UXH8(49) UXH8(57)
                UXH8(65) UXH8(73) UXH8(81) UXH8(89) UXH8(97) UXH8(105) UXH8(113)
                UXH(121) UXH(122) UXH(123) UXH(124) UXH(125) UXH(126) UXH(127)
                default: break;
            }
        }

        // ---- argmax shuffle chain issues now; hides under the FMA stream below ----
        MAXCHAIN();

        // ---- remaining columns, quarter-guarded (col k+1 re-update is a no-op:
        //      its broadcast row was annihilated; dead columns are never read) ----
        if (ps < 64) {
            if (k < 31) QL(0)
            if (k < 63) QL(32)
            if (k < 95) QL(64)
            QL(96)
        } else {
            if (k < 31) QH(0)
            if (k < 63) QH(32)
            if (k < 95) QH(64)
            QH(96)
        }
    }

    // ---------- final pivot (k = 127) ----------
    {
        const unsigned long long blo = __ballot(mlo == cmax);
        const unsigned long long bhi = __ballot(mhi == cmax);
        int p;
        if (blo)      p = __ffsll(blo) - 1;
        else if (bhi) p = 64 + __ffsll(bhi) - 1;
        else          p = 0;
        const int ps = __builtin_amdgcn_readfirstlane(p);
        const float pv = rdlane(ps >= 64 ? chi : clo, ps & 63);
        if (lane == 0) plist[127] = ps;
        acc += __log2f(fabsf(pv));
        neg += (pv < 0.f) ? 1 : 0;
    }

    // ---------- permutation parity + output (lane 0) ----------
    __syncthreads();
    if (lane == 0) {
        unsigned long long vis0 = 0, vis1 = 0;
        int ncyc = 0;
        for (int k2 = 0; k2 < 128; ++k2) {
            const bool seen = (k2 < 64) ? ((vis0 >> k2) & 1) : ((vis1 >> (k2 - 64)) & 1);
            if (!seen) {
                ++ncyc;
                int j = k2;
                do {
                    if (j < 64) vis0 |= 1ULL << j; else vis1 |= 1ULL << (j - 64);
                    j = plist[j];
                } while (j != k2);
            }
        }
        const int par = (128 - ncyc) & 1;
        out[b]         = acc * 0.69314718055994531f;      // log2 -> ln
        out[batch + b] = ((neg + par) & 1) ? 3.14159265358979f : 0.f;
    }
}

extern "C" void kernel_launch(void* const* d_in, const int* in_sizes, int n_in,
                              void* d_out, int out_size, void* d_ws, size_t ws_size,
                              hipStream_t stream) {
    const int*   n   = (const int*)d_in[0];     // [B, 256] int32
    const float* M   = (const float*)d_in[1];   // [256, 128] float32
    float*       out = (float*)d_out;           // planar complex: [B reals][B imags]

    const int batch = in_sizes[0] / NORB;       // 4096
    slogdet_pp3_kernel<<<batch, 64, 0, stream>>>(n, M, out, batch);
}

// Round 9
// 1070.071 us; speedup vs baseline: 1.9022x; 1.9022x over previous
//
#include <hip/hip_runtime.h>
#include <math.h>

#define NORB 256
#define NF 128

// ---- pivot lane writes its row quarter [Q0, Q0+32) to urow (float4) ----
#define WQ(Q0) { _Pragma("unroll") for (int j4 = (Q0)/4; j4 < (Q0)/4 + 8; ++j4) { \
    ((float4*)urow)[j4] = make_float4(r[4*j4+0], r[4*j4+1], r[4*j4+2], r[4*j4+3]); } }

// ---- plain quarter update: r[j] += l * urow[j] ----
#define Q(Q0) { _Pragma("unroll") for (int j4 = (Q0)/4; j4 < (Q0)/4 + 8; ++j4) { \
    const float4 u4 = ((const float4*)urow)[j4]; \
    r[4*j4+0] = fmaf(l, u4.x, r[4*j4+0]); \
    r[4*j4+1] = fmaf(l, u4.y, r[4*j4+1]); \
    r[4*j4+2] = fmaf(l, u4.z, r[4*j4+2]); \
    r[4*j4+3] = fmaf(l, u4.w, r[4*j4+3]); } }

// ---- quarter update + capture of column e (uniform selects) ----
#define QC(Q0) { _Pragma("unroll") for (int j4 = (Q0)/4; j4 < (Q0)/4 + 8; ++j4) { \
    const float4 u4 = ((const float4*)urow)[j4]; \
    r[4*j4+0] = fmaf(l, u4.x, r[4*j4+0]); if (4*j4+0 == e) curn = r[4*j4+0]; \
    r[4*j4+1] = fmaf(l, u4.y, r[4*j4+1]); if (4*j4+1 == e) curn = r[4*j4+1]; \
    r[4*j4+2] = fmaf(l, u4.z, r[4*j4+2]); if (4*j4+2 == e) curn = r[4*j4+2]; \
    r[4*j4+3] = fmaf(l, u4.w, r[4*j4+3]); if (4*j4+3 == e) curn = r[4*j4+3]; } }

__global__ __launch_bounds__(128, 2)
void slogdet_2w_kernel(const int* __restrict__ n, const float* __restrict__ M,
                       float* __restrict__ out, int batch)
{
    __shared__ int   R[NF];
    __shared__ int   plist[NF];
    __shared__ unsigned long long wpk[2];
    __shared__ float pivs;
    __shared__ __align__(16) float urow[NF];
    __shared__ int   segc[4];

    const int t    = threadIdx.x;   // 0..127 = row id
    const int lane = t & 63;
    const int wid  = t >> 6;
    const int b    = blockIdx.x;

    // ---------- occupied orbital indices, ascending ----------
    const unsigned long long lt = (1ULL << lane) - 1ULL;
    const int occA = (n[b * NORB + t] != 0);         // orbitals 0..127   (seg wid)
    const int occB = (n[b * NORB + 128 + t] != 0);   // orbitals 128..255 (seg 2+wid)
    const unsigned long long mA = __ballot(occA);
    const unsigned long long mB = __ballot(occB);
    if (lane == 0) { segc[wid] = __popcll(mA); segc[2 + wid] = __popcll(mB); }
    __syncthreads();
    {
        int offA = 0;
        for (int s = 0; s < wid; ++s) offA += segc[s];
        int offB = segc[0] + segc[1];
        for (int s = 2; s < 2 + wid; ++s) offB += segc[s];
        if (occA) R[offA + __popcll(mA & lt)] = t;
        if (occB) R[offB + __popcll(mB & lt)] = 128 + t;
    }
    __syncthreads();

    // ---------- gather my row into registers ----------
    float r[NF];
    {
        const float4* mr = (const float4*)(M + R[t] * NF);
        #pragma unroll
        for (int j4 = 0; j4 < 32; ++j4) {
            const float4 v = mr[j4];
            r[4*j4+0] = v.x; r[4*j4+1] = v.y; r[4*j4+2] = v.z; r[4*j4+3] = v.w;
        }
    }

    bool  alive = true;
    float cur   = r[0];     // my element of the current pivot-search column
    float acc   = 0.f;      // sum log2|piv|  (redundant on all lanes)
    int   neg   = 0;

    #pragma unroll 1
    for (int k = 0; k < 128; ++k) {
        // ---- argmax |cur| over alive rows: packed (keybits<<32 | 127-row) ----
        const float key = alive ? fabsf(cur) : 0.f;
        unsigned long long pk =
            ((unsigned long long)__float_as_uint(key) << 32) | (unsigned)(NF - 1 - t);
        #pragma unroll
        for (int mm = 32; mm; mm >>= 1) {
            const unsigned long long o = __shfl_xor(pk, mm);
            if (o > pk) pk = o;
        }
        if (lane == 0) wpk[wid] = pk;
        __syncthreads();
        const unsigned long long g0 = wpk[0], g1 = wpk[1];
        const unsigned long long g  = g0 > g1 ? g0 : g1;
        const int  prow  = NF - 1 - (int)(g & 0xffffffffu);
        const bool ispiv = (t == prow);

        // ---- pivot lane publishes pivot value + its row (active quarters) ----
        if (ispiv) {
            pivs = cur;
            plist[k] = t;
            if (k < 31) WQ(0)
            if (k < 63) WQ(32)
            if (k < 95) WQ(64)
            WQ(96)
        }
        __syncthreads();

        const float piv = pivs;
        acc += __log2f(fabsf(piv));
        neg += (piv < 0.f) ? 1 : 0;

        const float rp = 1.0f / piv;
        const float l  = (alive && !ispiv) ? (-cur * rp) : 0.f;  // retired/pivot rows inert
        alive = alive && !ispiv;

        if (k == 127) break;

        // ---- rank-1 update of my row (guarded quarters) + capture column e ----
        const int e = k + 1;
        float curn = 0.f;
        if (k < 31) QC(0)
        if (k < 63) { if (k >= 31) QC(32) else Q(32) }
        if (k < 95) { if (k >= 63) QC(64) else Q(64) }
        if (k >= 95) QC(96) else Q(96)
        cur = curn;
    }

    // ---------- permutation parity + output ----------
    __syncthreads();
    if (t == 0) {
        unsigned long long vis0 = 0, vis1 = 0;
        int ncyc = 0;
        for (int k2 = 0; k2 < 128; ++k2) {
            const bool seen = (k2 < 64) ? ((vis0 >> k2) & 1) : ((vis1 >> (k2 - 64)) & 1);
            if (!seen) {
                ++ncyc;
                int j = k2;
                do {
                    if (j < 64) vis0 |= 1ULL << j; else vis1 |= 1ULL << (j - 64);
                    j = plist[j];
                } while (j != k2);
            }
        }
        const int par = (128 - ncyc) & 1;
        out[b]         = acc * 0.69314718055994531f;   // log2 -> ln
        out[batch + b] = ((neg + par) & 1) ? 3.14159265358979f : 0.f;
    }
}

extern "C" void kernel_launch(void* const* d_in, const int* in_sizes, int n_in,
                              void* d_out, int out_size, void* d_ws, size_t ws_size,
                              hipStream_t stream) {
    const int*   n   = (const int*)d_in[0];     // [B, 256] int32
    const float* M   = (const float*)d_in[1];   // [256, 128] float32
    float*       out = (float*)d_out;           // planar complex: [B reals][B imags]

    const int batch = in_sizes[0] / NORB;       // 4096
    slogdet_2w_kernel<<<batch, 128, 0, stream>>>(n, M, out, batch);
}